// Round 8
// baseline (627.099 us; speedup 1.0000x reference)
//
#include <hip/hip_runtime.h>
#include <hip/hip_bf16.h>

#define N_NODES 100000
#define N_EDGES 1600000
#define IN_C 128
#define HID_C 256
#define OUT_C 128

typedef __attribute__((ext_vector_type(8))) short bf16x8;
typedef __attribute__((ext_vector_type(4))) float f32x4;
typedef __attribute__((ext_vector_type(2))) float f32x2;

static __device__ __forceinline__ short f2bf(float f) {
    union { float f; unsigned u; } x{f};
    unsigned r = (x.u + 0x7fffu + ((x.u >> 16) & 1u)) >> 16;
    return (short)r;
}
static __device__ __forceinline__ f32x2 bfpair(unsigned d) {
    union { unsigned u; float f; } lo, hi;
    lo.u = d << 16;
    hi.u = d & 0xffff0000u;
    return f32x2{lo.f, hi.f};
}

// ================= CSR build =================
// Pass 1: histogram with NON-returning atomicAdd (fire-and-forget; no wave
// stall on the return path) + all bf16 casts fused in (streaming work overlaps
// the atomic phase). No rank array (saves a 12.8 MB round-trip): the scatter
// claims positions via a returning atomicAdd on cursor[] (init = row_start).
__global__ void hist_cast(const int* __restrict__ rows, int* __restrict__ deg, int E,
                          const float* __restrict__ s0, short* __restrict__ d0, int n0,
                          const float* __restrict__ s1, short* __restrict__ d1, int n1,
                          const float* __restrict__ s2, short* __restrict__ d2, int n2,
                          const float* __restrict__ s3, short* __restrict__ d3, int n3)
{
    int idx = blockIdx.x * blockDim.x + threadIdx.x;
    if (idx < E) {
        atomicAdd(&deg[rows[idx]], 1);   // result unused -> no-return form
    } else {
        int i = (idx - E) * 4;
        int castN = n0 + n1 + n2 + n3;
        if (i >= castN) return;
        const float* s; short* d;
        if (i < n0) { s = s0; d = d0; }
        else if ((i -= n0) < n1) { s = s1; d = d1; }
        else if ((i -= n1) < n2) { s = s2; d = d2; }
        else { i -= n2; s = s3; d = d3; }
        float4 v = *(const float4*)(s + i);
        *(short4*)(d + i) = short4{f2bf(v.x), f2bf(v.y), f2bf(v.z), f2bf(v.w)};
    }
}

#define SCAN_BLOCK 256
#define SCAN_ELEMS 1024

__global__ __launch_bounds__(SCAN_BLOCK) void scan1(const int* __restrict__ deg,
                                                    int* __restrict__ excl,
                                                    int* __restrict__ bsum, int N)
{
    __shared__ int sh[SCAN_BLOCK];
    int t = threadIdx.x;
    int base = blockIdx.x * SCAN_ELEMS + t * 4;
    int v[4];
    #pragma unroll
    for (int i = 0; i < 4; ++i) {
        int idx = base + i;
        v[i] = (idx < N) ? deg[idx] : 0;
    }
    int s = v[0] + v[1] + v[2] + v[3];
    sh[t] = s;
    __syncthreads();
    for (int d = 1; d < SCAN_BLOCK; d <<= 1) {
        int add = (t >= d) ? sh[t - d] : 0;
        __syncthreads();
        sh[t] += add;
        __syncthreads();
    }
    int p = sh[t] - s;
    #pragma unroll
    for (int i = 0; i < 4; ++i) {
        int idx = base + i;
        if (idx < N) excl[idx] = p;
        p += v[i];
    }
    if (t == SCAN_BLOCK - 1) bsum[blockIdx.x] = sh[t];
}

// scan2 folded in: every block recomputes the (<=128-entry) block-sum prefix in
// LDS. Writes final row_start AND initializes cursor[] for the atomic scatter.
__global__ void scan3(int* __restrict__ row_start, int* __restrict__ cursor,
                      const int* __restrict__ bsum, int NB, int N, int E)
{
    __shared__ int pref[128];
    int t = threadIdx.x;
    if (t < 128) pref[t] = (t < NB) ? bsum[t] : 0;
    __syncthreads();
    for (int d = 1; d < 128; d <<= 1) {
        int add = (t < 128 && t >= d) ? pref[t - d] : 0;
        __syncthreads();
        if (t < 128) pref[t] += add;
        __syncthreads();
    }
    int i = blockIdx.x * blockDim.x + t;
    if (i < N) {
        int b = i >> 10;
        int v = row_start[i] + ((b == 0) ? 0 : pref[b - 1]);
        row_start[i] = v;
        cursor[i] = v;
    } else if (i == N) {
        row_start[N] = E;
    }
}

// scatter: claim position via returning atomicAdd on cursor (order within a
// row is arbitrary -- the gather is order-agnostic; accumulation order was
// already nondeterministic with ranks).
__global__ void scatter_epk(const int* __restrict__ rows, const int* __restrict__ cols,
                            const float* __restrict__ vals, int* __restrict__ cursor,
                            int2* __restrict__ epk, int E)
{
    int idx = blockIdx.x * blockDim.x + threadIdx.x;
    if (idx >= E) return;
    int pos = atomicAdd(&cursor[rows[idx]], 1);
    epk[pos] = int2{cols[idx], __float_as_int(vals[idx])};
}

// ================= quad-packed gather SpMM (C=128) =================
// 4 edges per wave-wide VMEM instruction: lane group g=lane>>4 owns edge j+4b+g,
// each lane loads uint4 (16B); 16 lanes cover one 256B row. Each lane holds ONE
// edge descriptor (no-spill form). Folds: shfl_xor 16 then 32.
template<int B>
static __device__ __forceinline__ void quad_batch(
    const unsigned* __restrict__ Hb, const int2* __restrict__ epk,
    int j, int sel, int loff, f32x2* acc)
{
    int2 e[B];
    #pragma unroll
    for (int b = 0; b < B; ++b) e[b] = epk[j + 4 * b + sel];
    uint4 g[B];
    #pragma unroll
    for (int b = 0; b < B; ++b)
        g[b] = *(const uint4*)(Hb + (size_t)e[b].x * 64 + loff);
    #pragma unroll
    for (int b = 0; b < B; ++b) {
        const float v = __int_as_float(e[b].y);
        acc[0] += v * bfpair(g[b].x);
        acc[1] += v * bfpair(g[b].y);
        acc[2] += v * bfpair(g[b].z);
        acc[3] += v * bfpair(g[b].w);
    }
}

// MODE 0: write bf16 row [N,128]. MODE 2: +bias, L2-normalize, write fp32 row.
template<int MODE>
__global__ __launch_bounds__(256) void spmm_gather_q(
    const short* __restrict__ H, const int* __restrict__ row_start,
    const int2* __restrict__ epk, void* __restrict__ outv,
    const float* __restrict__ bias, int N)
{
    const int wid = threadIdx.x >> 6;
    const int lane = threadIdx.x & 63;
    const int sel = lane >> 4;          // 0..3: which edge of the quad
    const int l15 = lane & 15;
    const int loff = l15 * 4;           // unsigned units; 16 lanes x 4 = 64 = full row
    const int row = blockIdx.x * 4 + wid;
    if (row >= N) return;
    int j = row_start[row];
    const int end = row_start[row + 1];
    const unsigned* Hb = (const unsigned*)H;

    f32x2 acc[4] = {};

    for (; j + 16 <= end; j += 16) quad_batch<4>(Hb, epk, j, sel, loff, acc);
    for (; j + 4 <= end; j += 4)   quad_batch<1>(Hb, epk, j, sel, loff, acc);
    if (j < end) {
        const int rem = end - j;        // 1..3 leftover edges; extra groups weight 0
        int2 e = epk[j + (sel < rem ? sel : rem - 1)];
        uint4 g = *(const uint4*)(Hb + (size_t)e.x * 64 + loff);
        const float v = (sel < rem) ? __int_as_float(e.y) : 0.f;
        acc[0] += v * bfpair(g.x);
        acc[1] += v * bfpair(g.y);
        acc[2] += v * bfpair(g.z);
        acc[3] += v * bfpair(g.w);
    }

    // fold the 4 edge-group partial sums
    #pragma unroll
    for (int u = 0; u < 4; ++u) {
        acc[u].x += __shfl_xor(acc[u].x, 16);
        acc[u].y += __shfl_xor(acc[u].y, 16);
        acc[u].x += __shfl_xor(acc[u].x, 32);
        acc[u].y += __shfl_xor(acc[u].y, 32);
    }

    if constexpr (MODE == 0) {
        if (lane < 16) {
            unsigned od[4];
            #pragma unroll
            for (int u = 0; u < 4; ++u)
                od[u] = (unsigned)(unsigned short)f2bf(acc[u].x)
                      | ((unsigned)(unsigned short)f2bf(acc[u].y) << 16);
            *(uint4*)((unsigned*)outv + (size_t)row * 64 + loff) =
                uint4{od[0], od[1], od[2], od[3]};
        }
    } else {
        const int c0 = l15 * 8;         // 8 channels per lane
        float4 b0 = *(const float4*)(bias + c0);
        float4 b1 = *(const float4*)(bias + c0 + 4);
        float o0 = acc[0].x + b0.x, o1 = acc[0].y + b0.y;
        float o2 = acc[1].x + b0.z, o3 = acc[1].y + b0.w;
        float o4 = acc[2].x + b1.x, o5 = acc[2].y + b1.y;
        float o6 = acc[3].x + b1.z, o7 = acc[3].y + b1.w;
        float ss = o0*o0 + o1*o1 + o2*o2 + o3*o3 + o4*o4 + o5*o5 + o6*o6 + o7*o7;
        #pragma unroll
        for (int d = 1; d < 16; d <<= 1)
            ss += __shfl_xor(ss, d);
        float s = 1.0f / fmaxf(sqrtf(ss), 1e-12f);
        if (lane < 16) {
            float* orow = (float*)outv + (size_t)row * 128 + c0;
            *(float4*)orow       = float4{o0 * s, o1 * s, o2 * s, o3 * s};
            *(float4*)(orow + 4) = float4{o4 * s, o5 * s, o6 * s, o7 * s};
        }
    }
}

// ================= pair-packed gather SpMM (C=256, MODE 0) =================
template<int B>
static __device__ __forceinline__ void pair256_batch(
    const unsigned* __restrict__ Hb, const int2* __restrict__ epk,
    int j, int sel, int loff, f32x2* acc)
{
    int2 e[B];
    #pragma unroll
    for (int b = 0; b < B; ++b) e[b] = epk[j + 2 * b + sel];
    uint4 g[B];
    #pragma unroll
    for (int b = 0; b < B; ++b)
        g[b] = *(const uint4*)(Hb + (size_t)e[b].x * 128 + loff);
    #pragma unroll
    for (int b = 0; b < B; ++b) {
        const float v = __int_as_float(e[b].y);
        acc[0] += v * bfpair(g[b].x);
        acc[1] += v * bfpair(g[b].y);
        acc[2] += v * bfpair(g[b].z);
        acc[3] += v * bfpair(g[b].w);
    }
}

__global__ __launch_bounds__(256) void spmm_gather_p256(
    const short* __restrict__ H, const int* __restrict__ row_start,
    const int2* __restrict__ epk, void* __restrict__ outv, int N)
{
    const int wid = threadIdx.x >> 6;
    const int lane = threadIdx.x & 63;
    const int sel = lane >> 5;          // 0: even edge, 1: odd edge
    const int l31 = lane & 31;
    const int loff = l31 * 4;           // 32 lanes x 4 unsigneds = 128 = full row
    const int row = blockIdx.x * 4 + wid;
    if (row >= N) return;
    int j = row_start[row];
    const int end = row_start[row + 1];
    const unsigned* Hb = (const unsigned*)H;

    f32x2 acc[4] = {};

    for (; j + 8 <= end; j += 8) pair256_batch<4>(Hb, epk, j, sel, loff, acc);
    for (; j + 2 <= end; j += 2) pair256_batch<1>(Hb, epk, j, sel, loff, acc);
    if (j < end) {
        int2 e = epk[j];
        uint4 g = *(const uint4*)(Hb + (size_t)e.x * 128 + loff);
        const float v = sel ? 0.f : __int_as_float(e.y);
        acc[0] += v * bfpair(g.x);
        acc[1] += v * bfpair(g.y);
        acc[2] += v * bfpair(g.z);
        acc[3] += v * bfpair(g.w);
    }

    #pragma unroll
    for (int u = 0; u < 4; ++u) {
        acc[u].x += __shfl_xor(acc[u].x, 32);
        acc[u].y += __shfl_xor(acc[u].y, 32);
    }

    if (lane < 32) {
        unsigned od[4];
        #pragma unroll
        for (int u = 0; u < 4; ++u)
            od[u] = (unsigned)(unsigned short)f2bf(acc[u].x)
                  | ((unsigned)(unsigned short)f2bf(acc[u].y) << 16);
        *(uint4*)((unsigned*)outv + (size_t)row * 128 + loff) =
            uint4{od[0], od[1], od[2], od[3]};
    }
}

// ================= bf16 MFMA GEMM, 128x64 tile, XCD-aware swizzle =================
template<int K, int M, bool RELU, bool BIAS>
__global__ __launch_bounds__(256) void gemm_bf16(
    const short* __restrict__ A, const short* __restrict__ W,
    const float* __restrict__ bias, short* __restrict__ Y, int N)
{
    constexpr int MBLK = M / 64;
    constexpr int BK = 32;
    constexpr int PAD = 8;
    __shared__ short As[128][BK + PAD];
    __shared__ short Ws[64][BK + PAD];

    const int id = blockIdx.x;
    const int bx = (id / (8 * MBLK)) * 8 + (id & 7);
    const int by = (id >> 3) & (MBLK - 1);

    const int tid = threadIdx.x;
    const int wid = tid >> 6;
    const int lane = tid & 63;
    const int wm = wid & 1;
    const int wn = wid >> 1;
    const int l15 = lane & 15;
    const int quad = lane >> 4;
    const int bn = bx * 128;
    const int bm = by * 64;

    f32x4 acc[4][2] = {};

    for (int k0 = 0; k0 < K; k0 += BK) {
        #pragma unroll
        for (int c = 0; c < 2; ++c) {
            int chunk = tid + c * 256;
            int row = chunk >> 2;
            int koff = (chunk & 3) * 8;
            int gr = bn + row;
            ulonglong2 v = {0ull, 0ull};
            if (gr < N) v = *(const ulonglong2*)(A + (size_t)gr * K + k0 + koff);
            *(ulonglong2*)&As[row][koff] = v;
        }
        {
            int row = tid >> 2;
            int koff = (tid & 3) * 8;
            ulonglong2 v = *(const ulonglong2*)(W + (size_t)(bm + row) * K + k0 + koff);
            *(ulonglong2*)&Ws[row][koff] = v;
        }
        __syncthreads();

        bf16x8 aF[4], bF[2];
        #pragma unroll
        for (int mt = 0; mt < 4; ++mt)
            aF[mt] = *(const bf16x8*)&As[wm * 64 + mt * 16 + l15][quad * 8];
        #pragma unroll
        for (int nt = 0; nt < 2; ++nt)
            bF[nt] = *(const bf16x8*)&Ws[wn * 32 + nt * 16 + l15][quad * 8];

        #pragma unroll
        for (int mt = 0; mt < 4; ++mt)
            #pragma unroll
            for (int nt = 0; nt < 2; ++nt)
                acc[mt][nt] = __builtin_amdgcn_mfma_f32_16x16x32_bf16(
                    aF[mt], bF[nt], acc[mt][nt], 0, 0, 0);
        __syncthreads();
    }

    #pragma unroll
    for (int nt = 0; nt < 2; ++nt) {
        int col = bm + wn * 32 + nt * 16 + l15;
        float bv = BIAS ? bias[col] : 0.f;
        #pragma unroll
        for (int mt = 0; mt < 4; ++mt) {
            int row0 = bn + wm * 64 + mt * 16 + quad * 4;
            #pragma unroll
            for (int r = 0; r < 4; ++r) {
                int row = row0 + r;
                if (row < N) {
                    float v = acc[mt][nt][r] + bv;
                    if (RELU) v = fmaxf(v, 0.f);
                    Y[(size_t)row * M + col] = f2bf(v);
                }
            }
        }
    }
}

extern "C" void kernel_launch(void* const* d_in, const int* in_sizes, int n_in,
                              void* d_out, int out_size, void* d_ws, size_t ws_size,
                              hipStream_t stream) {
    const float* x        = (const float*)d_in[0];
    const int*   edge_row = (const int*)d_in[1];
    const int*   edge_col = (const int*)d_in[2];
    const float* edge_val = (const float*)d_in[3];
    const float* W1       = (const float*)d_in[4];
    const float* b1       = (const float*)d_in[5];
    const float* W2       = (const float*)d_in[6];
    const float* b2       = (const float*)d_in[7];
    const float* W3       = (const float*)d_in[8];
    const float* b3       = (const float*)d_in[9];
    float* out = (float*)d_out;

    const int N = N_NODES, E = N_EDGES;
    const int NB = (N + SCAN_ELEMS - 1) / SCAN_ELEMS;   // 98

    // workspace layout
    short* xbf = (short*)d_ws;                    // [N,128] bf16
    short* Hbf = xbf + (size_t)N * IN_C;          // [N,256] bf16 (spmm outputs / H3)
    short* Gbf = Hbf + (size_t)N * HID_C;         // [N,256] bf16
    short* W1b = Gbf + (size_t)N * HID_C;         // [256,128]
    short* W2b = W1b + HID_C * IN_C;              // [256,256]
    short* W3b = W2b + HID_C * HID_C;             // [128,256]
    int* deg = (int*)(((uintptr_t)(W3b + OUT_C * HID_C) + 15) & ~(uintptr_t)15);
    int* row_start = deg + N;                     // [N+1]
    int* cursor    = row_start + (N + 1);         // [N]
    int* bsum      = cursor + N;                  // [128]
    int2* epk      = (int2*)(((uintptr_t)(bsum + 128) + 15) & ~(uintptr_t)15);  // [E]

    // ---- build CSR (lean: no rank array) + casts ----
    hipMemsetAsync(deg, 0, N * sizeof(int), stream);
    {
        int n0 = N * IN_C, n1 = HID_C * IN_C, n2 = HID_C * HID_C, n3 = OUT_C * HID_C;
        int total = E + (n0 + n1 + n2 + n3) / 4;   // both parts wave-aligned (E%64==0)
        hist_cast<<<(total + 255) / 256, 256, 0, stream>>>(
            edge_row, deg, E,
            x, xbf, n0, W1, W1b, n1, W2, W2b, n2, W3, W3b, n3);
    }
    scan1<<<NB, SCAN_BLOCK, 0, stream>>>(deg, row_start, bsum, N);
    scan3<<<(N + 256) / 256, 256, 0, stream>>>(row_start, cursor, bsum, NB, N, E);
    scatter_epk<<<(E + 255) / 256, 256, 0, stream>>>(
        edge_row, edge_col, edge_val, cursor, epk, E);

    const int spmm_grid = (N + 3) / 4;
    const int GXP = ((N + 127) / 128 + 7) & ~7;   // padded strips (OOB guarded)

    // Layer 1: Hbf = spmm(xbf) [N,128] (quad-packed); Gbf = relu(Hbf@W1.T+b1)
    spmm_gather_q<0><<<spmm_grid, 256, 0, stream>>>(
        xbf, row_start, epk, Hbf, nullptr, N);
    gemm_bf16<IN_C, HID_C, true, true><<<GXP * (HID_C / 64), 256, 0, stream>>>(
        Hbf, W1b, b1, Gbf, N);

    // Layer 2: Hbf = spmm(Gbf) [N,256] (pair-packed); Gbf = relu(Hbf@W2.T+b2)
    spmm_gather_p256<<<spmm_grid, 256, 0, stream>>>(
        Gbf, row_start, epk, Hbf, N);
    gemm_bf16<HID_C, HID_C, true, true><<<GXP * (HID_C / 64), 256, 0, stream>>>(
        Hbf, W2b, b2, Gbf, N);

    // Layer 3: Hbf = Gbf@W3.T [N,128]; out = normalize(spmm(Hbf) + b3) (quad)
    gemm_bf16<HID_C, OUT_C, false, false><<<GXP * (OUT_C / 64), 256, 0, stream>>>(
        Gbf, W3b, nullptr, Hbf, N);
    spmm_gather_q<2><<<spmm_grid, 256, 0, stream>>>(
        Hbf, row_start, epk, out, b3, N);
}

// Round 9
// 563.837 us; speedup vs baseline: 1.1122x; 1.1122x over previous
//
#include <hip/hip_runtime.h>
#include <hip/hip_bf16.h>

#define N_NODES 100000
#define N_EDGES 1600000
#define IN_C 128
#define HID_C 256
#define OUT_C 128

typedef __attribute__((ext_vector_type(8))) short bf16x8;
typedef __attribute__((ext_vector_type(4))) float f32x4;
typedef __attribute__((ext_vector_type(2))) float f32x2;

static __device__ __forceinline__ short f2bf(float f) {
    union { float f; unsigned u; } x{f};
    unsigned r = (x.u + 0x7fffu + ((x.u >> 16) & 1u)) >> 16;
    return (short)r;
}
static __device__ __forceinline__ f32x2 bfpair(unsigned d) {
    union { unsigned u; float f; } lo, hi;
    lo.u = d << 16;
    hi.u = d & 0xffff0000u;
    return f32x2{lo.f, hi.f};
}

// ================= CSR build =================
// Pass 1: histogram with RETURNING atomicAdd -> rank[e] (round-5 form: the
// rank makes the scatter atomic-free and dependency-free). The bf16 casts are
// fused HERE (not in the scatter): round-8 counters showed the atomic phase is
// latency-bound with BW/VALU idle (VALUBusy 0.4%, HBM 11%) -- streaming casts
// overlap the atomic latency instead of competing with scatter writebacks.
__global__ void hist_rank_cast(const int* __restrict__ rows, int* __restrict__ deg,
                               int* __restrict__ rank, int E,
                               const float* __restrict__ s0, short* __restrict__ d0, int n0,
                               const float* __restrict__ s1, short* __restrict__ d1, int n1,
                               const float* __restrict__ s2, short* __restrict__ d2, int n2,
                               const float* __restrict__ s3, short* __restrict__ d3, int n3)
{
    int idx = blockIdx.x * blockDim.x + threadIdx.x;
    if (idx < E) {
        rank[idx] = atomicAdd(&deg[rows[idx]], 1);
    } else {
        int i = (idx - E) * 4;
        int castN = n0 + n1 + n2 + n3;
        if (i >= castN) return;
        const float* s; short* d;
        if (i < n0) { s = s0; d = d0; }
        else if ((i -= n0) < n1) { s = s1; d = d1; }
        else if ((i -= n1) < n2) { s = s2; d = d2; }
        else { i -= n2; s = s3; d = d3; }
        float4 v = *(const float4*)(s + i);
        *(short4*)(d + i) = short4{f2bf(v.x), f2bf(v.y), f2bf(v.z), f2bf(v.w)};
    }
}

#define SCAN_BLOCK 256
#define SCAN_ELEMS 1024

__global__ __launch_bounds__(SCAN_BLOCK) void scan1(const int* __restrict__ deg,
                                                    int* __restrict__ excl,
                                                    int* __restrict__ bsum, int N)
{
    __shared__ int sh[SCAN_BLOCK];
    int t = threadIdx.x;
    int base = blockIdx.x * SCAN_ELEMS + t * 4;
    int v[4];
    #pragma unroll
    for (int i = 0; i < 4; ++i) {
        int idx = base + i;
        v[i] = (idx < N) ? deg[idx] : 0;
    }
    int s = v[0] + v[1] + v[2] + v[3];
    sh[t] = s;
    __syncthreads();
    for (int d = 1; d < SCAN_BLOCK; d <<= 1) {
        int add = (t >= d) ? sh[t - d] : 0;
        __syncthreads();
        sh[t] += add;
        __syncthreads();
    }
    int p = sh[t] - s;
    #pragma unroll
    for (int i = 0; i < 4; ++i) {
        int idx = base + i;
        if (idx < N) excl[idx] = p;
        p += v[i];
    }
    if (t == SCAN_BLOCK - 1) bsum[blockIdx.x] = sh[t];
}

// scan2 folded in: every block recomputes the (<=128-entry) block-sum prefix in LDS.
__global__ void scan3(int* __restrict__ row_start, const int* __restrict__ bsum,
                      int NB, int N, int E)
{
    __shared__ int pref[128];
    int t = threadIdx.x;
    if (t < 128) pref[t] = (t < NB) ? bsum[t] : 0;
    __syncthreads();
    for (int d = 1; d < 128; d <<= 1) {
        int add = (t < 128 && t >= d) ? pref[t - d] : 0;
        __syncthreads();
        if (t < 128) pref[t] += add;
        __syncthreads();
    }
    int i = blockIdx.x * blockDim.x + t;
    if (i < N) {
        int b = i >> 10;
        row_start[i] += (b == 0) ? 0 : pref[b - 1];
    } else if (i == N) {
        row_start[N] = E;
    }
}

// atomic-free scatter (no casts -- they moved to pass 1): no serializing
// dependency; the random epk line-writebacks get the full write path.
__global__ void scatter_epk(const int* __restrict__ rows, const int* __restrict__ cols,
                            const float* __restrict__ vals, const int* __restrict__ row_start,
                            const int* __restrict__ rank, int2* __restrict__ epk, int E)
{
    int idx = blockIdx.x * blockDim.x + threadIdx.x;
    if (idx >= E) return;
    int pos = row_start[rows[idx]] + rank[idx];
    epk[pos] = int2{cols[idx], __float_as_int(vals[idx])};
}

// ================= quad-packed gather SpMM (C=128) =================
// 4 edges per wave-wide VMEM instruction: lane group g=lane>>4 owns edge j+4b+g,
// each lane loads uint4 (16B); 16 lanes cover one 256B row. Each lane holds ONE
// edge descriptor (no-spill form). Folds: shfl_xor 16 then 32.
template<int B>
static __device__ __forceinline__ void quad_batch(
    const unsigned* __restrict__ Hb, const int2* __restrict__ epk,
    int j, int sel, int loff, f32x2* acc)
{
    int2 e[B];
    #pragma unroll
    for (int b = 0; b < B; ++b) e[b] = epk[j + 4 * b + sel];
    uint4 g[B];
    #pragma unroll
    for (int b = 0; b < B; ++b)
        g[b] = *(const uint4*)(Hb + (size_t)e[b].x * 64 + loff);
    #pragma unroll
    for (int b = 0; b < B; ++b) {
        const float v = __int_as_float(e[b].y);
        acc[0] += v * bfpair(g[b].x);
        acc[1] += v * bfpair(g[b].y);
        acc[2] += v * bfpair(g[b].z);
        acc[3] += v * bfpair(g[b].w);
    }
}

// MODE 0: write bf16 row [N,128]. MODE 2: +bias, L2-normalize, write fp32 row.
template<int MODE>
__global__ __launch_bounds__(256) void spmm_gather_q(
    const short* __restrict__ H, const int* __restrict__ row_start,
    const int2* __restrict__ epk, void* __restrict__ outv,
    const float* __restrict__ bias, int N)
{
    const int wid = threadIdx.x >> 6;
    const int lane = threadIdx.x & 63;
    const int sel = lane >> 4;          // 0..3: which edge of the quad
    const int l15 = lane & 15;
    const int loff = l15 * 4;           // unsigned units; 16 lanes x 4 = 64 = full row
    const int row = blockIdx.x * 4 + wid;
    if (row >= N) return;
    int j = row_start[row];
    const int end = row_start[row + 1];
    const unsigned* Hb = (const unsigned*)H;

    f32x2 acc[4] = {};

    for (; j + 16 <= end; j += 16) quad_batch<4>(Hb, epk, j, sel, loff, acc);
    for (; j + 4 <= end; j += 4)   quad_batch<1>(Hb, epk, j, sel, loff, acc);
    if (j < end) {
        const int rem = end - j;        // 1..3 leftover edges; extra groups weight 0
        int2 e = epk[j + (sel < rem ? sel : rem - 1)];
        uint4 g = *(const uint4*)(Hb + (size_t)e.x * 64 + loff);
        const float v = (sel < rem) ? __int_as_float(e.y) : 0.f;
        acc[0] += v * bfpair(g.x);
        acc[1] += v * bfpair(g.y);
        acc[2] += v * bfpair(g.z);
        acc[3] += v * bfpair(g.w);
    }

    // fold the 4 edge-group partial sums
    #pragma unroll
    for (int u = 0; u < 4; ++u) {
        acc[u].x += __shfl_xor(acc[u].x, 16);
        acc[u].y += __shfl_xor(acc[u].y, 16);
        acc[u].x += __shfl_xor(acc[u].x, 32);
        acc[u].y += __shfl_xor(acc[u].y, 32);
    }

    if constexpr (MODE == 0) {
        if (lane < 16) {
            unsigned od[4];
            #pragma unroll
            for (int u = 0; u < 4; ++u)
                od[u] = (unsigned)(unsigned short)f2bf(acc[u].x)
                      | ((unsigned)(unsigned short)f2bf(acc[u].y) << 16);
            *(uint4*)((unsigned*)outv + (size_t)row * 64 + loff) =
                uint4{od[0], od[1], od[2], od[3]};
        }
    } else {
        const int c0 = l15 * 8;         // 8 channels per lane
        float4 b0 = *(const float4*)(bias + c0);
        float4 b1 = *(const float4*)(bias + c0 + 4);
        float o0 = acc[0].x + b0.x, o1 = acc[0].y + b0.y;
        float o2 = acc[1].x + b0.z, o3 = acc[1].y + b0.w;
        float o4 = acc[2].x + b1.x, o5 = acc[2].y + b1.y;
        float o6 = acc[3].x + b1.z, o7 = acc[3].y + b1.w;
        float ss = o0*o0 + o1*o1 + o2*o2 + o3*o3 + o4*o4 + o5*o5 + o6*o6 + o7*o7;
        #pragma unroll
        for (int d = 1; d < 16; d <<= 1)
            ss += __shfl_xor(ss, d);
        float s = 1.0f / fmaxf(sqrtf(ss), 1e-12f);
        if (lane < 16) {
            float* orow = (float*)outv + (size_t)row * 128 + c0;
            *(float4*)orow       = float4{o0 * s, o1 * s, o2 * s, o3 * s};
            *(float4*)(orow + 4) = float4{o4 * s, o5 * s, o6 * s, o7 * s};
        }
    }
}

// ================= pair-packed gather SpMM (C=256, MODE 0) =================
template<int B>
static __device__ __forceinline__ void pair256_batch(
    const unsigned* __restrict__ Hb, const int2* __restrict__ epk,
    int j, int sel, int loff, f32x2* acc)
{
    int2 e[B];
    #pragma unroll
    for (int b = 0; b < B; ++b) e[b] = epk[j + 2 * b + sel];
    uint4 g[B];
    #pragma unroll
    for (int b = 0; b < B; ++b)
        g[b] = *(const uint4*)(Hb + (size_t)e[b].x * 128 + loff);
    #pragma unroll
    for (int b = 0; b < B; ++b) {
        const float v = __int_as_float(e[b].y);
        acc[0] += v * bfpair(g[b].x);
        acc[1] += v * bfpair(g[b].y);
        acc[2] += v * bfpair(g[b].z);
        acc[3] += v * bfpair(g[b].w);
    }
}

__global__ __launch_bounds__(256) void spmm_gather_p256(
    const short* __restrict__ H, const int* __restrict__ row_start,
    const int2* __restrict__ epk, void* __restrict__ outv, int N)
{
    const int wid = threadIdx.x >> 6;
    const int lane = threadIdx.x & 63;
    const int sel = lane >> 5;          // 0: even edge, 1: odd edge
    const int l31 = lane & 31;
    const int loff = l31 * 4;           // 32 lanes x 4 unsigneds = 128 = full row
    const int row = blockIdx.x * 4 + wid;
    if (row >= N) return;
    int j = row_start[row];
    const int end = row_start[row + 1];
    const unsigned* Hb = (const unsigned*)H;

    f32x2 acc[4] = {};

    for (; j + 8 <= end; j += 8) pair256_batch<4>(Hb, epk, j, sel, loff, acc);
    for (; j + 2 <= end; j += 2) pair256_batch<1>(Hb, epk, j, sel, loff, acc);
    if (j < end) {
        int2 e = epk[j];
        uint4 g = *(const uint4*)(Hb + (size_t)e.x * 128 + loff);
        const float v = sel ? 0.f : __int_as_float(e.y);
        acc[0] += v * bfpair(g.x);
        acc[1] += v * bfpair(g.y);
        acc[2] += v * bfpair(g.z);
        acc[3] += v * bfpair(g.w);
    }

    #pragma unroll
    for (int u = 0; u < 4; ++u) {
        acc[u].x += __shfl_xor(acc[u].x, 32);
        acc[u].y += __shfl_xor(acc[u].y, 32);
    }

    if (lane < 32) {
        unsigned od[4];
        #pragma unroll
        for (int u = 0; u < 4; ++u)
            od[u] = (unsigned)(unsigned short)f2bf(acc[u].x)
                  | ((unsigned)(unsigned short)f2bf(acc[u].y) << 16);
        *(uint4*)((unsigned*)outv + (size_t)row * 128 + loff) =
            uint4{od[0], od[1], od[2], od[3]};
    }
}

// ================= bf16 MFMA GEMM, 128x64 tile, XCD-aware swizzle =================
template<int K, int M, bool RELU, bool BIAS>
__global__ __launch_bounds__(256) void gemm_bf16(
    const short* __restrict__ A, const short* __restrict__ W,
    const float* __restrict__ bias, short* __restrict__ Y, int N)
{
    constexpr int MBLK = M / 64;
    constexpr int BK = 32;
    constexpr int PAD = 8;
    __shared__ short As[128][BK + PAD];
    __shared__ short Ws[64][BK + PAD];

    const int id = blockIdx.x;
    const int bx = (id / (8 * MBLK)) * 8 + (id & 7);
    const int by = (id >> 3) & (MBLK - 1);

    const int tid = threadIdx.x;
    const int wid = tid >> 6;
    const int lane = tid & 63;
    const int wm = wid & 1;
    const int wn = wid >> 1;
    const int l15 = lane & 15;
    const int quad = lane >> 4;
    const int bn = bx * 128;
    const int bm = by * 64;

    f32x4 acc[4][2] = {};

    for (int k0 = 0; k0 < K; k0 += BK) {
        #pragma unroll
        for (int c = 0; c < 2; ++c) {
            int chunk = tid + c * 256;
            int row = chunk >> 2;
            int koff = (chunk & 3) * 8;
            int gr = bn + row;
            ulonglong2 v = {0ull, 0ull};
            if (gr < N) v = *(const ulonglong2*)(A + (size_t)gr * K + k0 + koff);
            *(ulonglong2*)&As[row][koff] = v;
        }
        {
            int row = tid >> 2;
            int koff = (tid & 3) * 8;
            ulonglong2 v = *(const ulonglong2*)(W + (size_t)(bm + row) * K + k0 + koff);
            *(ulonglong2*)&Ws[row][koff] = v;
        }
        __syncthreads();

        bf16x8 aF[4], bF[2];
        #pragma unroll
        for (int mt = 0; mt < 4; ++mt)
            aF[mt] = *(const bf16x8*)&As[wm * 64 + mt * 16 + l15][quad * 8];
        #pragma unroll
        for (int nt = 0; nt < 2; ++nt)
            bF[nt] = *(const bf16x8*)&Ws[wn * 32 + nt * 16 + l15][quad * 8];

        #pragma unroll
        for (int mt = 0; mt < 4; ++mt)
            #pragma unroll
            for (int nt = 0; nt < 2; ++nt)
                acc[mt][nt] = __builtin_amdgcn_mfma_f32_16x16x32_bf16(
                    aF[mt], bF[nt], acc[mt][nt], 0, 0, 0);
        __syncthreads();
    }

    #pragma unroll
    for (int nt = 0; nt < 2; ++nt) {
        int col = bm + wn * 32 + nt * 16 + l15;
        float bv = BIAS ? bias[col] : 0.f;
        #pragma unroll
        for (int mt = 0; mt < 4; ++mt) {
            int row0 = bn + wm * 64 + mt * 16 + quad * 4;
            #pragma unroll
            for (int r = 0; r < 4; ++r) {
                int row = row0 + r;
                if (row < N) {
                    float v = acc[mt][nt][r] + bv;
                    if (RELU) v = fmaxf(v, 0.f);
                    Y[(size_t)row * M + col] = f2bf(v);
                }
            }
        }
    }
}

extern "C" void kernel_launch(void* const* d_in, const int* in_sizes, int n_in,
                              void* d_out, int out_size, void* d_ws, size_t ws_size,
                              hipStream_t stream) {
    const float* x        = (const float*)d_in[0];
    const int*   edge_row = (const int*)d_in[1];
    const int*   edge_col = (const int*)d_in[2];
    const float* edge_val = (const float*)d_in[3];
    const float* W1       = (const float*)d_in[4];
    const float* b1       = (const float*)d_in[5];
    const float* W2       = (const float*)d_in[6];
    const float* b2       = (const float*)d_in[7];
    const float* W3       = (const float*)d_in[8];
    const float* b3       = (const float*)d_in[9];
    float* out = (float*)d_out;

    const int N = N_NODES, E = N_EDGES;
    const int NB = (N + SCAN_ELEMS - 1) / SCAN_ELEMS;   // 98

    // workspace layout (round-5 scheme)
    short* xbf = (short*)d_ws;                    // [N,128] bf16
    short* Hbf = xbf + (size_t)N * IN_C;          // [N,256] bf16 (spmm outputs / H3)
    short* Gbf = Hbf + (size_t)N * HID_C;         // [N,256] bf16
    short* W1b = Gbf + (size_t)N * HID_C;         // [256,128]
    short* W2b = W1b + HID_C * IN_C;              // [256,256]
    short* W3b = W2b + HID_C * HID_C;             // [128,256]
    int* deg = (int*)(((uintptr_t)(W3b + OUT_C * HID_C) + 15) & ~(uintptr_t)15);
    int* row_start = deg + N;                     // [N+1]
    int* rank      = row_start + (N + 1);         // [E]
    int* bsum      = rank + E;                    // [128]
    int2* epk      = (int2*)(((uintptr_t)(bsum + 128) + 15) & ~(uintptr_t)15);  // [E]

    // ---- build CSR (rank-based, atomic-free scatter); casts overlap hist ----
    hipMemsetAsync(deg, 0, N * sizeof(int), stream);
    {
        int n0 = N * IN_C, n1 = HID_C * IN_C, n2 = HID_C * HID_C, n3 = OUT_C * HID_C;
        int total = E + (n0 + n1 + n2 + n3) / 4;   // both parts wave-aligned (E%64==0)
        hist_rank_cast<<<(total + 255) / 256, 256, 0, stream>>>(
            edge_row, deg, rank, E,
            x, xbf, n0, W1, W1b, n1, W2, W2b, n2, W3, W3b, n3);
    }
    scan1<<<NB, SCAN_BLOCK, 0, stream>>>(deg, row_start, bsum, N);
    scan3<<<(N + 256) / 256, 256, 0, stream>>>(row_start, bsum, NB, N, E);
    scatter_epk<<<(E + 255) / 256, 256, 0, stream>>>(
        edge_row, edge_col, edge_val, row_start, rank, epk, E);

    const int spmm_grid = (N + 3) / 4;
    const int GXP = ((N + 127) / 128 + 7) & ~7;   // padded strips (OOB guarded)

    // Layer 1: Hbf = spmm(xbf) [N,128] (quad-packed); Gbf = relu(Hbf@W1.T+b1)
    spmm_gather_q<0><<<spmm_grid, 256, 0, stream>>>(
        xbf, row_start, epk, Hbf, nullptr, N);
    gemm_bf16<IN_C, HID_C, true, true><<<GXP * (HID_C / 64), 256, 0, stream>>>(
        Hbf, W1b, b1, Gbf, N);

    // Layer 2: Hbf = spmm(Gbf) [N,256] (pair-packed); Gbf = relu(Hbf@W2.T+b2)
    spmm_gather_p256<<<spmm_grid, 256, 0, stream>>>(
        Gbf, row_start, epk, Hbf, N);
    gemm_bf16<HID_C, HID_C, true, true><<<GXP * (HID_C / 64), 256, 0, stream>>>(
        Hbf, W2b, b2, Gbf, N);

    // Layer 3: Hbf = Gbf@W3.T [N,128]; out = normalize(spmm(Hbf) + b3) (quad)
    gemm_bf16<HID_C, OUT_C, false, false><<<GXP * (OUT_C / 64), 256, 0, stream>>>(
        Gbf, W3b, nullptr, Hbf, N);
    spmm_gather_q<2><<<spmm_grid, 256, 0, stream>>>(
        Hbf, row_start, epk, out, b3, N);
}